// Round 2
// baseline (463.052 us; speedup 1.0000x reference)
//
#include <hip/hip_runtime.h>
#include <hip/hip_bf16.h>
#include <math.h>

typedef __bf16 bf16;
typedef __attribute__((ext_vector_type(8))) __bf16 bf16x8;
typedef __attribute__((ext_vector_type(4))) __bf16 bf16x4;
typedef __attribute__((ext_vector_type(4))) float f32x4;

#define D_DIM 2048
#define NKV   576

__device__ inline void gld_lds16(const void* g, void* l) {
    void* gg = const_cast<void*>(g);
    __builtin_amdgcn_global_load_lds(
        (__attribute__((address_space(1))) void*)gg,
        (__attribute__((address_space(3))) void*)l, 16, 0, 0);
}

// ---------------------------------------------------------------------------
// Generic 128x128x(BK=32) bf16 GEMM: C = A(MxK) @ B^T(NxK), batched over z.
// MODE 0: bf16 out. MODE 1: fp32 out. MODE 2: bf16 out, scale + kv-mask + N-guard.
// ---------------------------------------------------------------------------
template<int MODE>
__global__ __launch_bounds__(256) void gemm_bt(
    const bf16* __restrict__ A, const bf16* __restrict__ B, void* __restrict__ Cv,
    int M, int N, int K, int lda, int ldb, int ldc,
    long sAb, long sAh, long sBb, long sBh, long sCb, long sCh,
    const int* __restrict__ maskp, float scale)
{
    __shared__ __align__(16) bf16 As[128 * 32];
    __shared__ __align__(16) bf16 Bs[128 * 32];

    const int z  = blockIdx.z;
    const int bb = z >> 4, hh = z & 15;
    A += bb * sAb + hh * sAh;
    B += bb * sBb + hh * sBh;
    const long coff = bb * sCb + hh * sCh;

    const int m0 = blockIdx.y * 128, n0 = blockIdx.x * 128;
    const int tid = threadIdx.x, lane = tid & 63;
    const int wm = ((tid >> 6) >> 1) * 64, wn = ((tid >> 6) & 1) * 64;

    f32x4 acc[4][4] = {};
    const int fr = lane & 15, fo = (lane >> 4) * 8;

    for (int k0 = 0; k0 < K; k0 += 32) {
#pragma unroll
        for (int p = 0; p < 2; ++p) {
            const int c   = tid + p * 256;
            const int row = c >> 2, col = (c & 3) * 8;
            gld_lds16(A + (long)(m0 + row) * lda + (k0 + col), As + c * 8);
            int nrow = n0 + row;
            if (MODE == 2 && nrow >= N) nrow = N - 1;   // clamp, garbage unused
            gld_lds16(B + (long)nrow * ldb + (k0 + col), Bs + c * 8);
        }
        __syncthreads();

        bf16x8 af[4], bg[4];
#pragma unroll
        for (int i = 0; i < 4; ++i)
            af[i] = *(const bf16x8*)(As + (wm + i * 16 + fr) * 32 + fo);
#pragma unroll
        for (int j = 0; j < 4; ++j)
            bg[j] = *(const bf16x8*)(Bs + (wn + j * 16 + fr) * 32 + fo);
#pragma unroll
        for (int i = 0; i < 4; ++i)
#pragma unroll
            for (int j = 0; j < 4; ++j)
                acc[i][j] = __builtin_amdgcn_mfma_f32_16x16x32_bf16(
                    af[i], bg[j], acc[i][j], 0, 0, 0);
        __syncthreads();
    }

    // epilogue: C/D layout col=lane&15, row=(lane>>4)*4+reg  [m89-verified]
    const int er = (lane >> 4) * 4, ec = lane & 15;
#pragma unroll
    for (int i = 0; i < 4; ++i) {
#pragma unroll
        for (int j = 0; j < 4; ++j) {
            const int n = n0 + wn + j * 16 + ec;
            if (MODE == 2 && n >= N) continue;
            float addm = 0.f;
            if (MODE == 2) {
                const bool valid = (n < 64) || (maskp[bb * 512 + (n - 64)] != 0);
                addm = valid ? 0.f : -1e30f;
            }
#pragma unroll
            for (int r = 0; r < 4; ++r) {
                const int m = m0 + wm + i * 16 + er + r;
                float v = acc[i][j][r];
                if (MODE == 2) v = v * scale + addm;
                if (MODE == 1)
                    ((float*)Cv)[coff + (long)m * ldc + n] = v;
                else
                    ((bf16*)Cv)[coff + (long)m * ldc + n] = (bf16)v;
            }
        }
    }
}

// ---------------------------------------------------------------------------
// RMSNorm (D=2048) + cast to bf16. One block per row.
// out row = (r/rpb)*ostride + ooff + r%rpb   (handles kv concat placement)
// ---------------------------------------------------------------------------
__global__ __launch_bounds__(256) void rmsnorm_cast(
    const float* __restrict__ x, const float* __restrict__ w, bf16* __restrict__ y,
    int rpb, int ostride, int ooff)
{
    const int r = blockIdx.x;
    const float* xr = x + (long)r * D_DIM;
    bf16* yr = y + ((long)(r / rpb) * ostride + ooff + (r % rpb)) * D_DIM;
    const int t = threadIdx.x;

    float4 v0 = *(const float4*)(xr + t * 4);
    float4 v1 = *(const float4*)(xr + 1024 + t * 4);
    float ss = v0.x * v0.x + v0.y * v0.y + v0.z * v0.z + v0.w * v0.w
             + v1.x * v1.x + v1.y * v1.y + v1.z * v1.z + v1.w * v1.w;
#pragma unroll
    for (int off = 32; off; off >>= 1) ss += __shfl_xor(ss, off);
    __shared__ float p[4];
    if ((t & 63) == 0) p[t >> 6] = ss;
    __syncthreads();
    const float rs = rsqrtf((p[0] + p[1] + p[2] + p[3]) * (1.0f / 2048.0f) + 1e-6f);

    float4 w0 = *(const float4*)(w + t * 4);
    float4 w1 = *(const float4*)(w + 1024 + t * 4);
    bf16x4 o0 = { (bf16)(v0.x * rs * w0.x), (bf16)(v0.y * rs * w0.y),
                  (bf16)(v0.z * rs * w0.z), (bf16)(v0.w * rs * w0.w) };
    bf16x4 o1 = { (bf16)(v1.x * rs * w1.x), (bf16)(v1.y * rs * w1.y),
                  (bf16)(v1.z * rs * w1.z), (bf16)(v1.w * rs * w1.w) };
    *(bf16x4*)(yr + t * 4) = o0;
    *(bf16x4*)(yr + 1024 + t * 4) = o1;
}

// ---------------------------------------------------------------------------
// Cast 2048x2048 fp32 weight -> bf16, transposed (out[n][k] = in[k][n]).
// ---------------------------------------------------------------------------
__global__ __launch_bounds__(256) void wcast_t(
    const float* __restrict__ w0, const float* __restrict__ w1,
    const float* __restrict__ w2, const float* __restrict__ w3,
    bf16* __restrict__ o0, bf16* __restrict__ o1,
    bf16* __restrict__ o2, bf16* __restrict__ o3)
{
    const float* in; bf16* out;
    switch (blockIdx.z) {
        case 0:  in = w0; out = o0; break;
        case 1:  in = w1; out = o1; break;
        case 2:  in = w2; out = o2; break;
        default: in = w3; out = o3; break;
    }
    __shared__ float tile[32][33];
    const int t  = threadIdx.x;
    const int r0 = blockIdx.y * 32, c0 = blockIdx.x * 32;
    const int r = t >> 3, c = (t & 7) * 4;
    float4 v = *(const float4*)(in + (long)(r0 + r) * 2048 + c0 + c);
    tile[r][c] = v.x; tile[r][c + 1] = v.y; tile[r][c + 2] = v.z; tile[r][c + 3] = v.w;
    __syncthreads();
    bf16x4 o = { (bf16)tile[c][r], (bf16)tile[c + 1][r],
                 (bf16)tile[c + 2][r], (bf16)tile[c + 3][r] };
    *(bf16x4*)(out + (long)(c0 + r) * 2048 + r0 + c) = o;
}

// ---------------------------------------------------------------------------
// v (B,Nkv,H,HD) -> vT (B,H,HD,Nkv)
// ---------------------------------------------------------------------------
__global__ __launch_bounds__(256) void vtrans(
    const bf16* __restrict__ v, bf16* __restrict__ vt)
{
    const int z = blockIdx.z, bb = z >> 4, hh = z & 15;
    __shared__ bf16 tile[32][36];
    const int t  = threadIdx.x;
    const int d0 = blockIdx.x * 32, s0 = blockIdx.y * 32;
    const int r = t >> 3, c = (t & 7) * 4;
    bf16x4 val = *(const bf16x4*)(v + (long)(bb * NKV + s0 + r) * 2048 + hh * 128 + d0 + c);
    tile[r][c] = val[0]; tile[r][c + 1] = val[1];
    tile[r][c + 2] = val[2]; tile[r][c + 3] = val[3];
    __syncthreads();
    bf16x4 o = { tile[c][r], tile[c + 1][r], tile[c + 2][r], tile[c + 3][r] };
    *(bf16x4*)(vt + ((long)z * 128 + d0 + r) * NKV + s0 + c) = o;
}

// ---------------------------------------------------------------------------
// In-place softmax over rows of 576 bf16. One wave per row.
// ---------------------------------------------------------------------------
__global__ __launch_bounds__(256) void softmax_inplace(bf16* __restrict__ S, int rows)
{
    const int wid  = blockIdx.x * 4 + (threadIdx.x >> 6);
    const int lane = threadIdx.x & 63;
    if (wid >= rows) return;
    bf16* row = S + (long)wid * NKV;

    bf16x8 c0 = *(const bf16x8*)(row + lane * 8);
    const bool has2 = lane < 8;
    bf16x8 c1 = {};
    if (has2) c1 = *(const bf16x8*)(row + 512 + lane * 8);

    float f0[8], f1[8];
    float mx = -1e30f;
#pragma unroll
    for (int j = 0; j < 8; ++j) { f0[j] = (float)c0[j]; mx = fmaxf(mx, f0[j]); }
    if (has2) {
#pragma unroll
        for (int j = 0; j < 8; ++j) { f1[j] = (float)c1[j]; mx = fmaxf(mx, f1[j]); }
    }
#pragma unroll
    for (int off = 32; off; off >>= 1) mx = fmaxf(mx, __shfl_xor(mx, off));

    float s = 0.f;
#pragma unroll
    for (int j = 0; j < 8; ++j) { f0[j] = __expf(f0[j] - mx); s += f0[j]; }
    if (has2) {
#pragma unroll
        for (int j = 0; j < 8; ++j) { f1[j] = __expf(f1[j] - mx); s += f1[j]; }
    }
#pragma unroll
    for (int off = 32; off; off >>= 1) s += __shfl_xor(s, off);
    const float inv = 1.0f / s;

    bf16x8 o0;
#pragma unroll
    for (int j = 0; j < 8; ++j) o0[j] = (bf16)(f0[j] * inv);
    *(bf16x8*)(row + lane * 8) = o0;
    if (has2) {
        bf16x8 o1;
#pragma unroll
        for (int j = 0; j < 8; ++j) o1[j] = (bf16)(f1[j] * inv);
        *(bf16x8*)(row + 512 + lane * 8) = o1;
    }
}

// ---------------------------------------------------------------------------
extern "C" void kernel_launch(void* const* d_in, const int* in_sizes, int n_in,
                              void* d_out, int out_size, void* d_ws, size_t ws_size,
                              hipStream_t stream)
{
    const float* hidden = (const float*)d_in[0];
    const float* wsp    = (const float*)d_in[1];
    const float* corr   = (const float*)d_in[2];
    const int*   cmask  = (const int*)d_in[3];
    const float* lnq    = (const float*)d_in[4];
    const float* lnkv   = (const float*)d_in[5];
    const float* Wq     = (const float*)d_in[6];
    const float* Wk     = (const float*)d_in[7];
    const float* Wv     = (const float*)d_in[8];
    const float* Wo     = (const float*)d_in[9];
    float* out = (float*)d_out;

    char* ws = (char*)d_ws;
    size_t off = 0;
    auto alloc = [&](size_t sz) { void* p = ws + off; off += (sz + 255) & ~(size_t)255; return p; };

    bf16* WqT = (bf16*)alloc(2048ull * 2048 * 2);   // W^T layouts (N,K)
    bf16* WkT = (bf16*)alloc(2048ull * 2048 * 2);
    bf16* WvT = (bf16*)alloc(2048ull * 2048 * 2);
    bf16* WoT = (bf16*)alloc(2048ull * 2048 * 2);
    bf16* hb  = (bf16*)alloc(4096ull * 2048 * 2);   // rmsnorm(hidden)
    bf16* kvb = (bf16*)alloc(1152ull * 2048 * 2);   // rmsnorm([ws;corr])
    bf16* qb  = (bf16*)alloc(4096ull * 2048 * 2);
    bf16* kb  = (bf16*)alloc(1152ull * 2048 * 2);
    bf16* vb  = (bf16*)alloc(1152ull * 2048 * 2);
    bf16* vtb = (bf16*)alloc(1152ull * 2048 * 2);   // (B,H,HD,Nkv)
    bf16* Sb  = (bf16*)alloc(2ull * 16 * 2048 * NKV * 2); // scores -> attn in-place
    bf16* aob = (bf16*)alloc(4096ull * 2048 * 2);   // attn output (B,T,INNER)

    // 1) weights -> bf16 transposed
    wcast_t<<<dim3(64, 64, 4), 256, 0, stream>>>(Wq, Wk, Wv, Wo, WqT, WkT, WvT, WoT);
    // 2) rmsnorm + cast
    rmsnorm_cast<<<4096, 256, 0, stream>>>(hidden, lnq, hb, 2048, 2048, 0);
    rmsnorm_cast<<<128, 256, 0, stream>>>(wsp, lnkv, kvb, 64, NKV, 0);
    rmsnorm_cast<<<1024, 256, 0, stream>>>(corr, lnkv, kvb, 512, NKV, 64);
    // 3) projections
    gemm_bt<0><<<dim3(16, 32, 1), 256, 0, stream>>>(hb, WqT, qb, 4096, 2048, 2048,
        2048, 2048, 2048, 0, 0, 0, 0, 0, 0, nullptr, 1.f);
    gemm_bt<0><<<dim3(16, 9, 1), 256, 0, stream>>>(kvb, WkT, kb, 1152, 2048, 2048,
        2048, 2048, 2048, 0, 0, 0, 0, 0, 0, nullptr, 1.f);
    gemm_bt<0><<<dim3(16, 9, 1), 256, 0, stream>>>(kvb, WvT, vb, 1152, 2048, 2048,
        2048, 2048, 2048, 0, 0, 0, 0, 0, 0, nullptr, 1.f);
    // 4) V transpose per head
    vtrans<<<dim3(4, 18, 32), 256, 0, stream>>>(vb, vtb);
    // 5) scores = q @ k^T * scale + mask  (batched over (b,h); z = b*16+h)
    gemm_bt<2><<<dim3(5, 16, 32), 256, 0, stream>>>(qb, kb, Sb, 2048, NKV, 128,
        2048, 2048, NKV,
        (long)2048 * 2048,            // qb batch stride (2048 rows x 2048)  -- FIXED
        128,
        (long)NKV * 2048, 128,
        (long)16 * 2048 * NKV, (long)2048 * NKV,
        cmask, 0.08838834764831845f);
    // 6) softmax in place
    softmax_inplace<<<16384, 256, 0, stream>>>(Sb, 2 * 16 * 2048);
    // 7) O = attn @ V   (A=(T,Nkv), B^T = vT (HD,Nkv)) -> (B,T,H,HD)
    gemm_bt<0><<<dim3(1, 16, 32), 256, 0, stream>>>(Sb, vtb, aob, 2048, 128, NKV,
        NKV, NKV, 2048,
        (long)16 * 2048 * NKV, (long)2048 * NKV,
        (long)16 * 128 * NKV, (long)128 * NKV,
        (long)2048 * 2048, 128,
        nullptr, 1.f);
    // 8) final: out = attn_out @ Wo  (fp32 output)
    gemm_bt<1><<<dim3(16, 32, 1), 256, 0, stream>>>(aob, WoT, out, 4096, 2048, 2048,
        2048, 2048, 2048, 0, 0, 0, 0, 0, 0, nullptr, 1.f);
}

// Round 3
// 419.791 us; speedup vs baseline: 1.1031x; 1.1031x over previous
//
#include <hip/hip_runtime.h>
#include <hip/hip_bf16.h>
#include <math.h>

typedef __bf16 bf16;
typedef __attribute__((ext_vector_type(8))) __bf16 bf16x8;
typedef __attribute__((ext_vector_type(4))) __bf16 bf16x4;
typedef __attribute__((ext_vector_type(4))) float f32x4;

#define D_DIM 2048
#define NKV   576

__device__ inline void gld_lds16(const void* g, void* l) {
    void* gg = const_cast<void*>(g);
    __builtin_amdgcn_global_load_lds(
        (__attribute__((address_space(1))) void*)gg,
        (__attribute__((address_space(3))) void*)l, 16, 0, 0);
}

// ---------------------------------------------------------------------------
// Generic 128x128x(BK=32) bf16 GEMM: C = A(MxK) @ B^T(NxK).
// MODE 0: bf16 out. MODE 1: fp32 out.
// ---------------------------------------------------------------------------
template<int MODE>
__global__ __launch_bounds__(256) void gemm_bt(
    const bf16* __restrict__ A, const bf16* __restrict__ B, void* __restrict__ Cv,
    int M, int N, int K, int lda, int ldb, int ldc)
{
    __shared__ __align__(16) bf16 As[128 * 32];
    __shared__ __align__(16) bf16 Bs[128 * 32];

    const int m0 = blockIdx.y * 128, n0 = blockIdx.x * 128;
    const int tid = threadIdx.x, lane = tid & 63;
    const int wm = ((tid >> 6) >> 1) * 64, wn = ((tid >> 6) & 1) * 64;

    f32x4 acc[4][4] = {};
    const int fr = lane & 15, fo = (lane >> 4) * 8;

    for (int k0 = 0; k0 < K; k0 += 32) {
#pragma unroll
        for (int p = 0; p < 2; ++p) {
            const int c   = tid + p * 256;
            const int row = c >> 2, col = (c & 3) * 8;
            gld_lds16(A + (long)(m0 + row) * lda + (k0 + col), As + c * 8);
            gld_lds16(B + (long)(n0 + row) * ldb + (k0 + col), Bs + c * 8);
        }
        __syncthreads();

        bf16x8 af[4], bg[4];
#pragma unroll
        for (int i = 0; i < 4; ++i)
            af[i] = *(const bf16x8*)(As + (wm + i * 16 + fr) * 32 + fo);
#pragma unroll
        for (int j = 0; j < 4; ++j)
            bg[j] = *(const bf16x8*)(Bs + (wn + j * 16 + fr) * 32 + fo);
#pragma unroll
        for (int i = 0; i < 4; ++i)
#pragma unroll
            for (int j = 0; j < 4; ++j)
                acc[i][j] = __builtin_amdgcn_mfma_f32_16x16x32_bf16(
                    af[i], bg[j], acc[i][j], 0, 0, 0);
        __syncthreads();
    }

    const int er = (lane >> 4) * 4, ec = lane & 15;
#pragma unroll
    for (int i = 0; i < 4; ++i) {
#pragma unroll
        for (int j = 0; j < 4; ++j) {
            const int n = n0 + wn + j * 16 + ec;
#pragma unroll
            for (int r = 0; r < 4; ++r) {
                const int m = m0 + wm + i * 16 + er + r;
                float v = acc[i][j][r];
                if (MODE == 1)
                    ((float*)Cv)[(long)m * ldc + n] = v;
                else
                    ((bf16*)Cv)[(long)m * ldc + n] = (bf16)v;
            }
        }
    }
}

// ---------------------------------------------------------------------------
// RMSNorm (D=2048) + cast to bf16.
// ---------------------------------------------------------------------------
__global__ __launch_bounds__(256) void rmsnorm_cast(
    const float* __restrict__ x, const float* __restrict__ w, bf16* __restrict__ y,
    int rpb, int ostride, int ooff)
{
    const int r = blockIdx.x;
    const float* xr = x + (long)r * D_DIM;
    bf16* yr = y + ((long)(r / rpb) * ostride + ooff + (r % rpb)) * D_DIM;
    const int t = threadIdx.x;

    float4 v0 = *(const float4*)(xr + t * 4);
    float4 v1 = *(const float4*)(xr + 1024 + t * 4);
    float ss = v0.x * v0.x + v0.y * v0.y + v0.z * v0.z + v0.w * v0.w
             + v1.x * v1.x + v1.y * v1.y + v1.z * v1.z + v1.w * v1.w;
#pragma unroll
    for (int off = 32; off; off >>= 1) ss += __shfl_xor(ss, off);
    __shared__ float p[4];
    if ((t & 63) == 0) p[t >> 6] = ss;
    __syncthreads();
    const float rs = rsqrtf((p[0] + p[1] + p[2] + p[3]) * (1.0f / 2048.0f) + 1e-6f);

    float4 w0 = *(const float4*)(w + t * 4);
    float4 w1 = *(const float4*)(w + 1024 + t * 4);
    bf16x4 o0 = { (bf16)(v0.x * rs * w0.x), (bf16)(v0.y * rs * w0.y),
                  (bf16)(v0.z * rs * w0.z), (bf16)(v0.w * rs * w0.w) };
    bf16x4 o1 = { (bf16)(v1.x * rs * w1.x), (bf16)(v1.y * rs * w1.y),
                  (bf16)(v1.z * rs * w1.z), (bf16)(v1.w * rs * w1.w) };
    *(bf16x4*)(yr + t * 4) = o0;
    *(bf16x4*)(yr + 1024 + t * 4) = o1;
}

// ---------------------------------------------------------------------------
// Cast 2048x2048 fp32 weight -> bf16, transposed.
// ---------------------------------------------------------------------------
__global__ __launch_bounds__(256) void wcast_t(
    const float* __restrict__ w0, const float* __restrict__ w1,
    const float* __restrict__ w2, const float* __restrict__ w3,
    bf16* __restrict__ o0, bf16* __restrict__ o1,
    bf16* __restrict__ o2, bf16* __restrict__ o3)
{
    const float* in; bf16* out;
    switch (blockIdx.z) {
        case 0:  in = w0; out = o0; break;
        case 1:  in = w1; out = o1; break;
        case 2:  in = w2; out = o2; break;
        default: in = w3; out = o3; break;
    }
    __shared__ float tile[32][33];
    const int t  = threadIdx.x;
    const int r0 = blockIdx.y * 32, c0 = blockIdx.x * 32;
    const int r = t >> 3, c = (t & 7) * 4;
    float4 v = *(const float4*)(in + (long)(r0 + r) * 2048 + c0 + c);
    tile[r][c] = v.x; tile[r][c + 1] = v.y; tile[r][c + 2] = v.z; tile[r][c + 3] = v.w;
    __syncthreads();
    bf16x4 o = { (bf16)tile[c][r], (bf16)tile[c + 1][r],
                 (bf16)tile[c + 2][r], (bf16)tile[c + 3][r] };
    *(bf16x4*)(out + (long)(c0 + r) * 2048 + r0 + c) = o;
}

// ---------------------------------------------------------------------------
// V part of kvout (B,576,4096) at col 2048+h*128 -> vt (B,H,128,576)
// ---------------------------------------------------------------------------
__global__ __launch_bounds__(256) void vtrans(
    const bf16* __restrict__ kv, bf16* __restrict__ vt)
{
    const int z = blockIdx.z, bb = z >> 4, hh = z & 15;
    __shared__ bf16 tile[32][36];
    const int t  = threadIdx.x;
    const int d0 = blockIdx.x * 32, s0 = blockIdx.y * 32;
    const int r = t >> 3, c = (t & 7) * 4;
    bf16x4 val = *(const bf16x4*)(kv + (long)(bb * NKV + s0 + r) * 4096 + 2048 + hh * 128 + d0 + c);
    tile[r][c] = val[0]; tile[r][c + 1] = val[1];
    tile[r][c + 2] = val[2]; tile[r][c + 3] = val[3];
    __syncthreads();
    bf16x4 o = { tile[c][r], tile[c + 1][r], tile[c + 2][r], tile[c + 3][r] };
    *(bf16x4*)(vt + ((long)z * 128 + d0 + r) * NKV + s0 + c) = o;
}

// ---------------------------------------------------------------------------
// Flash attention: q-tile 64, kv-chunk 64 (9 chunks), online softmax.
// Q (B,T,2048) col h*128 | KV (B,576,4096) K at col h*128 | VT (B,H,128,576)
// O (B,T,2048) col h*128.  grid (T/64, H, B), 256 threads.
// ---------------------------------------------------------------------------
__global__ __launch_bounds__(256) void flash_attn(
    const bf16* __restrict__ Q, const bf16* __restrict__ KV,
    const bf16* __restrict__ VT, const int* __restrict__ cmask,
    bf16* __restrict__ O)
{
    __shared__ __align__(16) bf16 Qs[64 * 128];   // 16KB
    __shared__ __align__(16) bf16 Ks[64 * 128];   // 16KB, reused as Ps (stride 72)
    __shared__ __align__(16) bf16 VTs[128 * 64];  // 16KB

    const int qt = blockIdx.x, h = blockIdx.y, b = blockIdx.z;
    const int tid = threadIdx.x, lane = tid & 63, w = tid >> 6;
    const int fr = lane & 15, fg = lane >> 4;

    const bf16* qbase = Q + ((long)(b * 2048 + qt * 64)) * 2048 + h * 128;
#pragma unroll
    for (int p = 0; p < 4; ++p) {
        int c = p * 256 + tid;
        gld_lds16(qbase + (long)(c >> 4) * 2048 + (c & 15) * 8, Qs + c * 8);
    }

    float m_r[4], l_r[4];
    f32x4 acc_o[8];
#pragma unroll
    for (int r = 0; r < 4; ++r) { m_r[r] = -3.0e38f; l_r[r] = 0.f; }
#pragma unroll
    for (int j = 0; j < 8; ++j) acc_o[j] = (f32x4){0.f, 0.f, 0.f, 0.f};

    const float scale2 = 0.12752792330124195f;  // (1/sqrt(128)) * log2(e)
    const bf16* kbase = KV + (long)b * NKV * 4096 + h * 128;
    const bf16* vbase = VT + ((long)(b * 16 + h)) * 128 * NKV;

    for (int kc = 0; kc < 9; ++kc) {
        const int kv0 = kc * 64;
        // stage K chunk (64 x 128) and VT chunk (128 x 64)
#pragma unroll
        for (int p = 0; p < 4; ++p) {
            int c = p * 256 + tid;
            gld_lds16(kbase + (long)(kv0 + (c >> 4)) * 4096 + (c & 15) * 8, Ks + c * 8);
        }
#pragma unroll
        for (int p = 0; p < 4; ++p) {
            int c = p * 256 + tid;
            gld_lds16(vbase + (long)(c >> 3) * NKV + kv0 + (c & 7) * 8, VTs + c * 8);
        }
        __syncthreads();                     // (a) staging visible

        // S = Q @ K^T for this wave's 16 q-rows x 64 kv-cols
        f32x4 acc_s[4] = {};
#pragma unroll
        for (int s = 0; s < 4; ++s) {
            bf16x8 af = *(const bf16x8*)(Qs + (w * 16 + fr) * 128 + s * 32 + fg * 8);
#pragma unroll
            for (int j = 0; j < 4; ++j) {
                bf16x8 bg = *(const bf16x8*)(Ks + (j * 16 + fr) * 128 + s * 32 + fg * 8);
                acc_s[j] = __builtin_amdgcn_mfma_f32_16x16x32_bf16(af, bg, acc_s[j], 0, 0, 0);
            }
        }

        float bias[4];
#pragma unroll
        for (int j = 0; j < 4; ++j) {
            const int kv = kv0 + j * 16 + fr;
            const bool valid = (kv < 64) || (cmask[b * 512 + kv - 64] != 0);
            bias[j] = valid ? 0.f : -1e30f;
        }
        float s_f[4][4];
        float mc[4] = {-3.0e38f, -3.0e38f, -3.0e38f, -3.0e38f};
#pragma unroll
        for (int j = 0; j < 4; ++j)
#pragma unroll
            for (int r = 0; r < 4; ++r) {
                float v = fmaf(acc_s[j][r], scale2, bias[j]);
                s_f[j][r] = v; mc[r] = fmaxf(mc[r], v);
            }
#pragma unroll
        for (int r = 0; r < 4; ++r) {
            mc[r] = fmaxf(mc[r], __shfl_xor(mc[r], 1));
            mc[r] = fmaxf(mc[r], __shfl_xor(mc[r], 2));
            mc[r] = fmaxf(mc[r], __shfl_xor(mc[r], 4));
            mc[r] = fmaxf(mc[r], __shfl_xor(mc[r], 8));
        }
        float alpha[4];
#pragma unroll
        for (int r = 0; r < 4; ++r) {
            const float mn = fmaxf(m_r[r], mc[r]);
            alpha[r] = __builtin_amdgcn_exp2f(m_r[r] - mn);
            m_r[r] = mn;
        }
        float rs[4] = {0.f, 0.f, 0.f, 0.f};
#pragma unroll
        for (int j = 0; j < 4; ++j)
#pragma unroll
            for (int r = 0; r < 4; ++r) {
                const float pv = __builtin_amdgcn_exp2f(s_f[j][r] - m_r[r]);
                s_f[j][r] = pv; rs[r] += pv;
            }
#pragma unroll
        for (int r = 0; r < 4; ++r) {
            rs[r] += __shfl_xor(rs[r], 1);
            rs[r] += __shfl_xor(rs[r], 2);
            rs[r] += __shfl_xor(rs[r], 4);
            rs[r] += __shfl_xor(rs[r], 8);
            l_r[r] = l_r[r] * alpha[r] + rs[r];
        }
#pragma unroll
        for (int j = 0; j < 8; ++j)
#pragma unroll
            for (int r = 0; r < 4; ++r) acc_o[j][r] *= alpha[r];

        __syncthreads();                     // (b) all Ks reads done before overwrite

        // write P into Ks region, row stride 72 (16B-aligned rows, pad kills conflicts)
        bf16* Ps = Ks;
#pragma unroll
        for (int j = 0; j < 4; ++j)
#pragma unroll
            for (int r = 0; r < 4; ++r)
                Ps[(w * 16 + fg * 4 + r) * 72 + j * 16 + fr] = (bf16)s_f[j][r];
        // no barrier: each wave reads only the rows it wrote (in-order DS ops)

#pragma unroll
        for (int s2 = 0; s2 < 2; ++s2) {
            bf16x8 af = *(const bf16x8*)(Ps + (w * 16 + fr) * 72 + s2 * 32 + fg * 8);
#pragma unroll
            for (int jd = 0; jd < 8; ++jd) {
                bf16x8 bg = *(const bf16x8*)(VTs + (jd * 16 + fr) * 64 + s2 * 32 + fg * 8);
                acc_o[jd] = __builtin_amdgcn_mfma_f32_16x16x32_bf16(af, bg, acc_o[jd], 0, 0, 0);
            }
        }
        __syncthreads();                     // (d) P/VT reads done before next stage
    }

    bf16* obase = O + ((long)(b * 2048 + qt * 64)) * 2048 + h * 128;
#pragma unroll
    for (int r = 0; r < 4; ++r) {
        const float inv = 1.0f / l_r[r];
        const int row = w * 16 + fg * 4 + r;
#pragma unroll
        for (int jd = 0; jd < 8; ++jd)
            obase[(long)row * 2048 + jd * 16 + fr] = (bf16)(acc_o[jd][r] * inv);
    }
}

// ---------------------------------------------------------------------------
extern "C" void kernel_launch(void* const* d_in, const int* in_sizes, int n_in,
                              void* d_out, int out_size, void* d_ws, size_t ws_size,
                              hipStream_t stream)
{
    const float* hidden = (const float*)d_in[0];
    const float* wsp    = (const float*)d_in[1];
    const float* corr   = (const float*)d_in[2];
    const int*   cmask  = (const int*)d_in[3];
    const float* lnq    = (const float*)d_in[4];
    const float* lnkv   = (const float*)d_in[5];
    const float* Wq     = (const float*)d_in[6];
    const float* Wk     = (const float*)d_in[7];
    const float* Wv     = (const float*)d_in[8];
    const float* Wo     = (const float*)d_in[9];
    float* out = (float*)d_out;

    char* ws = (char*)d_ws;
    size_t off = 0;
    auto alloc = [&](size_t sz) { void* p = ws + off; off += (sz + 255) & ~(size_t)255; return p; };

    bf16* WqT   = (bf16*)alloc(2048ull * 2048 * 2);
    bf16* WkvT  = (bf16*)alloc(4096ull * 2048 * 2);   // [WkT ; WvT]
    bf16* WoT   = (bf16*)alloc(2048ull * 2048 * 2);
    bf16* hb    = (bf16*)alloc(4096ull * 2048 * 2);
    bf16* kvb   = (bf16*)alloc(1152ull * 2048 * 2);
    bf16* qb    = (bf16*)alloc(4096ull * 2048 * 2);
    bf16* kvout = (bf16*)alloc(1152ull * 4096 * 2);   // (B,576,4096): [K|V]
    bf16* vtb   = (bf16*)alloc(4096ull * NKV * 2);    // (B,H,128,576)
    bf16* aob   = (bf16*)alloc(4096ull * 2048 * 2);

    // 1) weights -> bf16 transposed (WkT,WvT stacked into WkvT)
    wcast_t<<<dim3(64, 64, 4), 256, 0, stream>>>(
        Wq, Wk, Wv, Wo, WqT, WkvT, WkvT + 2048ull * 2048, WoT);
    // 2) rmsnorm + cast
    rmsnorm_cast<<<4096, 256, 0, stream>>>(hidden, lnq, hb, 2048, 2048, 0);
    rmsnorm_cast<<<128, 256, 0, stream>>>(wsp, lnkv, kvb, 64, NKV, 0);
    rmsnorm_cast<<<1024, 256, 0, stream>>>(corr, lnkv, kvb, 512, NKV, 64);
    // 3) Q projection
    gemm_bt<0><<<dim3(16, 32, 1), 256, 0, stream>>>(hb, WqT, qb,
        4096, 2048, 2048, 2048, 2048, 2048);
    // 4) fused K+V projection (N=4096)
    gemm_bt<0><<<dim3(32, 9, 1), 256, 0, stream>>>(kvb, WkvT, kvout,
        1152, 4096, 2048, 2048, 2048, 4096);
    // 5) V transpose per head
    vtrans<<<dim3(4, 18, 32), 256, 0, stream>>>(kvout, vtb);
    // 6) fused flash attention
    flash_attn<<<dim3(32, 16, 2), 256, 0, stream>>>(qb, kvout, vtb, cmask, aob);
    // 7) final: out = attn_out @ Wo (fp32 out)
    gemm_bt<1><<<dim3(16, 32, 1), 256, 0, stream>>>(aob, WoT, out,
        4096, 2048, 2048, 2048, 2048, 2048);
}

// Round 4
// 382.934 us; speedup vs baseline: 1.2092x; 1.0962x over previous
//
#include <hip/hip_runtime.h>
#include <hip/hip_bf16.h>
#include <math.h>

typedef __bf16 bf16;
typedef __attribute__((ext_vector_type(8))) __bf16 bf16x8;
typedef __attribute__((ext_vector_type(4))) __bf16 bf16x4;
typedef __attribute__((ext_vector_type(4))) float f32x4;

#define D_DIM 2048
#define NKV   576

__device__ inline void gld_lds16(const void* g, void* l) {
    void* gg = const_cast<void*>(g);
    __builtin_amdgcn_global_load_lds(
        (__attribute__((address_space(1))) void*)gg,
        (__attribute__((address_space(3))) void*)l, 16, 0, 0);
}

// ---------------------------------------------------------------------------
// Generic 128x128x(BK=32) bf16 GEMM: C = A(MxK) @ B^T(NxK).
// MODE 0: bf16 out. MODE 1: fp32 out.
// ---------------------------------------------------------------------------
template<int MODE>
__global__ __launch_bounds__(256) void gemm_bt(
    const bf16* __restrict__ A, const bf16* __restrict__ B, void* __restrict__ Cv,
    int M, int N, int K, int lda, int ldb, int ldc)
{
    __shared__ __align__(16) bf16 As[128 * 32];
    __shared__ __align__(16) bf16 Bs[128 * 32];

    const int m0 = blockIdx.y * 128, n0 = blockIdx.x * 128;
    const int tid = threadIdx.x, lane = tid & 63;
    const int wm = ((tid >> 6) >> 1) * 64, wn = ((tid >> 6) & 1) * 64;

    f32x4 acc[4][4] = {};
    const int fr = lane & 15, fo = (lane >> 4) * 8;

    for (int k0 = 0; k0 < K; k0 += 32) {
#pragma unroll
        for (int p = 0; p < 2; ++p) {
            const int c   = tid + p * 256;
            const int row = c >> 2, col = (c & 3) * 8;
            gld_lds16(A + (long)(m0 + row) * lda + (k0 + col), As + c * 8);
            gld_lds16(B + (long)(n0 + row) * ldb + (k0 + col), Bs + c * 8);
        }
        __syncthreads();

        bf16x8 af[4], bg[4];
#pragma unroll
        for (int i = 0; i < 4; ++i)
            af[i] = *(const bf16x8*)(As + (wm + i * 16 + fr) * 32 + fo);
#pragma unroll
        for (int j = 0; j < 4; ++j)
            bg[j] = *(const bf16x8*)(Bs + (wn + j * 16 + fr) * 32 + fo);
#pragma unroll
        for (int i = 0; i < 4; ++i)
#pragma unroll
            for (int j = 0; j < 4; ++j)
                acc[i][j] = __builtin_amdgcn_mfma_f32_16x16x32_bf16(
                    af[i], bg[j], acc[i][j], 0, 0, 0);
        __syncthreads();
    }

    const int er = (lane >> 4) * 4, ec = lane & 15;
#pragma unroll
    for (int i = 0; i < 4; ++i) {
#pragma unroll
        for (int j = 0; j < 4; ++j) {
            const int n = n0 + wn + j * 16 + ec;
#pragma unroll
            for (int r = 0; r < 4; ++r) {
                const int m = m0 + wm + i * 16 + er + r;
                float v = acc[i][j][r];
                if (MODE == 1)
                    ((float*)Cv)[(long)m * ldc + n] = v;
                else
                    ((bf16*)Cv)[(long)m * ldc + n] = (bf16)v;
            }
        }
    }
}

// ---------------------------------------------------------------------------
// RMSNorm (D=2048) + cast to bf16.
// ---------------------------------------------------------------------------
__global__ __launch_bounds__(256) void rmsnorm_cast(
    const float* __restrict__ x, const float* __restrict__ w, bf16* __restrict__ y,
    int rpb, int ostride, int ooff)
{
    const int r = blockIdx.x;
    const float* xr = x + (long)r * D_DIM;
    bf16* yr = y + ((long)(r / rpb) * ostride + ooff + (r % rpb)) * D_DIM;
    const int t = threadIdx.x;

    float4 v0 = *(const float4*)(xr + t * 4);
    float4 v1 = *(const float4*)(xr + 1024 + t * 4);
    float ss = v0.x * v0.x + v0.y * v0.y + v0.z * v0.z + v0.w * v0.w
             + v1.x * v1.x + v1.y * v1.y + v1.z * v1.z + v1.w * v1.w;
#pragma unroll
    for (int off = 32; off; off >>= 1) ss += __shfl_xor(ss, off);
    __shared__ float p[4];
    if ((t & 63) == 0) p[t >> 6] = ss;
    __syncthreads();
    const float rs = rsqrtf((p[0] + p[1] + p[2] + p[3]) * (1.0f / 2048.0f) + 1e-6f);

    float4 w0 = *(const float4*)(w + t * 4);
    float4 w1 = *(const float4*)(w + 1024 + t * 4);
    bf16x4 o0 = { (bf16)(v0.x * rs * w0.x), (bf16)(v0.y * rs * w0.y),
                  (bf16)(v0.z * rs * w0.z), (bf16)(v0.w * rs * w0.w) };
    bf16x4 o1 = { (bf16)(v1.x * rs * w1.x), (bf16)(v1.y * rs * w1.y),
                  (bf16)(v1.z * rs * w1.z), (bf16)(v1.w * rs * w1.w) };
    *(bf16x4*)(yr + t * 4) = o0;
    *(bf16x4*)(yr + 1024 + t * 4) = o1;
}

// ---------------------------------------------------------------------------
// Cast 2048x2048 fp32 weight -> bf16, transposed.
// ---------------------------------------------------------------------------
__global__ __launch_bounds__(256) void wcast_t(
    const float* __restrict__ w0, const float* __restrict__ w1,
    const float* __restrict__ w2, const float* __restrict__ w3,
    bf16* __restrict__ o0, bf16* __restrict__ o1,
    bf16* __restrict__ o2, bf16* __restrict__ o3)
{
    const float* in; bf16* out;
    switch (blockIdx.z) {
        case 0:  in = w0; out = o0; break;
        case 1:  in = w1; out = o1; break;
        case 2:  in = w2; out = o2; break;
        default: in = w3; out = o3; break;
    }
    __shared__ float tile[32][33];
    const int t  = threadIdx.x;
    const int r0 = blockIdx.y * 32, c0 = blockIdx.x * 32;
    const int r = t >> 3, c = (t & 7) * 4;
    float4 v = *(const float4*)(in + (long)(r0 + r) * 2048 + c0 + c);
    tile[r][c] = v.x; tile[r][c + 1] = v.y; tile[r][c + 2] = v.z; tile[r][c + 3] = v.w;
    __syncthreads();
    bf16x4 o = { (bf16)tile[c][r], (bf16)tile[c + 1][r],
                 (bf16)tile[c + 2][r], (bf16)tile[c + 3][r] };
    *(bf16x4*)(out + (long)(c0 + r) * 2048 + r0 + c) = o;
}

// ---------------------------------------------------------------------------
// V part of kvout (B,576,4096) at col 2048+h*128 -> vt (B,H,128,576)
// ---------------------------------------------------------------------------
__global__ __launch_bounds__(256) void vtrans(
    const bf16* __restrict__ kv, bf16* __restrict__ vt)
{
    const int z = blockIdx.z, bb = z >> 4, hh = z & 15;
    __shared__ bf16 tile[32][36];
    const int t  = threadIdx.x;
    const int d0 = blockIdx.x * 32, s0 = blockIdx.y * 32;
    const int r = t >> 3, c = (t & 7) * 4;
    bf16x4 val = *(const bf16x4*)(kv + (long)(bb * NKV + s0 + r) * 4096 + 2048 + hh * 128 + d0 + c);
    tile[r][c] = val[0]; tile[r][c + 1] = val[1];
    tile[r][c + 2] = val[2]; tile[r][c + 3] = val[3];
    __syncthreads();
    bf16x4 o = { tile[c][r], tile[c + 1][r], tile[c + 2][r], tile[c + 3][r] };
    *(bf16x4*)(vt + ((long)z * 128 + d0 + r) * NKV + s0 + c) = o;
}

// ---------------------------------------------------------------------------
// Flash attention: q-tile 64, kv-chunk 64 (9 chunks), online softmax.
// Q fragments live in registers (invariant across chunks). K and VT chunks are
// staged via global_load_lds with an XOR-swizzled LDS layout:
//   Ks slot (r*16+cs) holds logical 16B-chunk cs^(r&15) of K-row r
//   VTs slot (r*8+cs)  holds logical 16B-chunk cs^(r&7)  of VT-row r
// so fragment reads hit banks 4*(cl^fr) mod 32 -> 2-way only (free).
// grid (T/64, H, B), 256 threads.
// ---------------------------------------------------------------------------
__global__ __launch_bounds__(256, 4) void flash_attn(
    const bf16* __restrict__ Q, const bf16* __restrict__ KV,
    const bf16* __restrict__ VT, const int* __restrict__ cmask,
    bf16* __restrict__ O)
{
    __shared__ __align__(16) bf16 Ks[64 * 128];   // 16KB, swizzled; reused as Ps
    __shared__ __align__(16) bf16 VTs[128 * 64];  // 16KB, swizzled

    const int qt = blockIdx.x, h = blockIdx.y, b = blockIdx.z;
    const int tid = threadIdx.x, lane = tid & 63, w = tid >> 6;
    const int fr = lane & 15, fg = lane >> 4;

    // Q fragments in registers: rows w*16+fr, k = s*32 + fg*8 .. +7
    const bf16* qbase = Q + ((long)(b * 2048 + qt * 64)) * 2048 + h * 128;
    bf16x8 qf[4];
#pragma unroll
    for (int s = 0; s < 4; ++s)
        qf[s] = *(const bf16x8*)(qbase + (long)(w * 16 + fr) * 2048 + s * 32 + fg * 8);

    float m_r[4], l_r[4];
    f32x4 acc_o[8];
#pragma unroll
    for (int r = 0; r < 4; ++r) { m_r[r] = -3.0e38f; l_r[r] = 0.f; }
#pragma unroll
    for (int j = 0; j < 8; ++j) acc_o[j] = (f32x4){0.f, 0.f, 0.f, 0.f};

    const float scale2 = 0.12752792330124195f;  // (1/sqrt(128)) * log2(e)
    const bf16* kbase = KV + (long)b * NKV * 4096 + h * 128;
    const bf16* vbase = VT + ((long)(b * 16 + h)) * 128 * NKV;

    for (int kc = 0; kc < 9; ++kc) {
        const int kv0 = kc * 64;
        // stage K chunk (64 rows x 16 chunks), XOR-swizzled source
#pragma unroll
        for (int p = 0; p < 4; ++p) {
            const int c = p * 256 + tid;
            const int r = c >> 4, cs = c & 15, cl = cs ^ (r & 15);
            gld_lds16(kbase + (long)(kv0 + r) * 4096 + cl * 8, Ks + c * 8);
        }
        // stage VT chunk (128 rows x 8 chunks), XOR-swizzled source
#pragma unroll
        for (int p = 0; p < 4; ++p) {
            const int c = p * 256 + tid;
            const int r = c >> 3, cs = c & 7, cl = cs ^ (r & 7);
            gld_lds16(vbase + (long)r * NKV + kv0 + cl * 8, VTs + c * 8);
        }
        __syncthreads();                     // (a) staging visible

        // S = Q @ K^T for this wave's 16 q-rows x 64 kv-cols
        f32x4 acc_s[4] = {};
#pragma unroll
        for (int s = 0; s < 4; ++s) {
#pragma unroll
            for (int j = 0; j < 4; ++j) {
                bf16x8 bg = *(const bf16x8*)(Ks +
                    ((j * 16 + fr) * 16 + ((s * 4 + fg) ^ fr)) * 8);
                acc_s[j] = __builtin_amdgcn_mfma_f32_16x16x32_bf16(qf[s], bg, acc_s[j], 0, 0, 0);
            }
        }

        float bias[4];
#pragma unroll
        for (int j = 0; j < 4; ++j) {
            const int kv = kv0 + j * 16 + fr;
            const bool valid = (kv < 64) || (cmask[b * 512 + kv - 64] != 0);
            bias[j] = valid ? 0.f : -1e30f;
        }
        float s_f[4][4];
        float mc[4] = {-3.0e38f, -3.0e38f, -3.0e38f, -3.0e38f};
#pragma unroll
        for (int j = 0; j < 4; ++j)
#pragma unroll
            for (int r = 0; r < 4; ++r) {
                float v = fmaf(acc_s[j][r], scale2, bias[j]);
                s_f[j][r] = v; mc[r] = fmaxf(mc[r], v);
            }
#pragma unroll
        for (int r = 0; r < 4; ++r) {
            mc[r] = fmaxf(mc[r], __shfl_xor(mc[r], 1));
            mc[r] = fmaxf(mc[r], __shfl_xor(mc[r], 2));
            mc[r] = fmaxf(mc[r], __shfl_xor(mc[r], 4));
            mc[r] = fmaxf(mc[r], __shfl_xor(mc[r], 8));
        }
        float alpha[4];
#pragma unroll
        for (int r = 0; r < 4; ++r) {
            const float mn = fmaxf(m_r[r], mc[r]);
            alpha[r] = __builtin_amdgcn_exp2f(m_r[r] - mn);
            m_r[r] = mn;
        }
        float rs[4] = {0.f, 0.f, 0.f, 0.f};
#pragma unroll
        for (int j = 0; j < 4; ++j)
#pragma unroll
            for (int r = 0; r < 4; ++r) {
                const float pv = __builtin_amdgcn_exp2f(s_f[j][r] - m_r[r]);
                s_f[j][r] = pv; rs[r] += pv;
            }
#pragma unroll
        for (int r = 0; r < 4; ++r) {
            rs[r] += __shfl_xor(rs[r], 1);
            rs[r] += __shfl_xor(rs[r], 2);
            rs[r] += __shfl_xor(rs[r], 4);
            rs[r] += __shfl_xor(rs[r], 8);
            l_r[r] = l_r[r] * alpha[r] + rs[r];
        }
#pragma unroll
        for (int j = 0; j < 8; ++j)
#pragma unroll
            for (int r = 0; r < 4; ++r) acc_o[j][r] *= alpha[r];

        __syncthreads();                     // (b) all Ks reads done before overwrite

        // write P into Ks region, row stride 72 (16B-aligned rows, no conflicts)
        bf16* Ps = Ks;
#pragma unroll
        for (int j = 0; j < 4; ++j)
#pragma unroll
            for (int r = 0; r < 4; ++r)
                Ps[(w * 16 + fg * 4 + r) * 72 + j * 16 + fr] = (bf16)s_f[j][r];
        // no barrier: each wave reads only the rows it wrote (in-order DS ops)

#pragma unroll
        for (int s2 = 0; s2 < 2; ++s2) {
            bf16x8 af = *(const bf16x8*)(Ps + (w * 16 + fr) * 72 + s2 * 32 + fg * 8);
#pragma unroll
            for (int jd = 0; jd < 8; ++jd) {
                bf16x8 bg = *(const bf16x8*)(VTs +
                    ((jd * 16 + fr) * 8 + ((s2 * 4 + fg) ^ (fr & 7))) * 8);
                acc_o[jd] = __builtin_amdgcn_mfma_f32_16x16x32_bf16(af, bg, acc_o[jd], 0, 0, 0);
            }
        }
        __syncthreads();                     // (c) P/VT reads done before next stage
    }

    bf16* obase = O + ((long)(b * 2048 + qt * 64)) * 2048 + h * 128;
#pragma unroll
    for (int r = 0; r < 4; ++r) {
        const float inv = 1.0f / l_r[r];
        const int row = w * 16 + fg * 4 + r;
#pragma unroll
        for (int jd = 0; jd < 8; ++jd)
            obase[(long)row * 2048 + jd * 16 + fr] = (bf16)(acc_o[jd][r] * inv);
    }
}

// ---------------------------------------------------------------------------
extern "C" void kernel_launch(void* const* d_in, const int* in_sizes, int n_in,
                              void* d_out, int out_size, void* d_ws, size_t ws_size,
                              hipStream_t stream)
{
    const float* hidden = (const float*)d_in[0];
    const float* wsp    = (const float*)d_in[1];
    const float* corr   = (const float*)d_in[2];
    const int*   cmask  = (const int*)d_in[3];
    const float* lnq    = (const float*)d_in[4];
    const float* lnkv   = (const float*)d_in[5];
    const float* Wq     = (const float*)d_in[6];
    const float* Wk     = (const float*)d_in[7];
    const float* Wv     = (const float*)d_in[8];
    const float* Wo     = (const float*)d_in[9];
    float* out = (float*)d_out;

    char* ws = (char*)d_ws;
    size_t off = 0;
    auto alloc = [&](size_t sz) { void* p = ws + off; off += (sz + 255) & ~(size_t)255; return p; };

    bf16* WqT   = (bf16*)alloc(2048ull * 2048 * 2);
    bf16* WkvT  = (bf16*)alloc(4096ull * 2048 * 2);   // [WkT ; WvT]
    bf16* WoT   = (bf16*)alloc(2048ull * 2048 * 2);
    bf16* hb    = (bf16*)alloc(4096ull * 2048 * 2);
    bf16* kvb   = (bf16*)alloc(1152ull * 2048 * 2);
    bf16* qb    = (bf16*)alloc(4096ull * 2048 * 2);
    bf16* kvout = (bf16*)alloc(1152ull * 4096 * 2);   // (B,576,4096): [K|V]
    bf16* vtb   = (bf16*)alloc(4096ull * NKV * 2);    // (B,H,128,576)
    bf16* aob   = (bf16*)alloc(4096ull * 2048 * 2);

    // 1) weights -> bf16 transposed (WkT,WvT stacked into WkvT)
    wcast_t<<<dim3(64, 64, 4), 256, 0, stream>>>(
        Wq, Wk, Wv, Wo, WqT, WkvT, WkvT + 2048ull * 2048, WoT);
    // 2) rmsnorm + cast
    rmsnorm_cast<<<4096, 256, 0, stream>>>(hidden, lnq, hb, 2048, 2048, 0);
    rmsnorm_cast<<<128, 256, 0, stream>>>(wsp, lnkv, kvb, 64, NKV, 0);
    rmsnorm_cast<<<1024, 256, 0, stream>>>(corr, lnkv, kvb, 512, NKV, 64);
    // 3) Q projection
    gemm_bt<0><<<dim3(16, 32, 1), 256, 0, stream>>>(hb, WqT, qb,
        4096, 2048, 2048, 2048, 2048, 2048);
    // 4) fused K+V projection (N=4096)
    gemm_bt<0><<<dim3(32, 9, 1), 256, 0, stream>>>(kvb, WkvT, kvout,
        1152, 4096, 2048, 2048, 2048, 4096);
    // 5) V transpose per head
    vtrans<<<dim3(4, 18, 32), 256, 0, stream>>>(kvout, vtb);
    // 6) fused flash attention
    flash_attn<<<dim3(32, 16, 2), 256, 0, stream>>>(qb, kvout, vtb, cmask, aob);
    // 7) final: out = attn_out @ Wo (fp32 out)
    gemm_bt<1><<<dim3(16, 32, 1), 256, 0, stream>>>(aob, WoT, out,
        4096, 2048, 2048, 2048, 2048, 2048);
}

// Round 5
// 330.952 us; speedup vs baseline: 1.3992x; 1.1571x over previous
//
#include <hip/hip_runtime.h>
#include <hip/hip_bf16.h>
#include <math.h>

typedef __bf16 bf16;
typedef __attribute__((ext_vector_type(8))) __bf16 bf16x8;
typedef __attribute__((ext_vector_type(4))) __bf16 bf16x4;
typedef __attribute__((ext_vector_type(4))) float f32x4;

#define D_DIM 2048
#define NKV   576

__device__ inline void gld_lds16(const void* g, void* l) {
    void* gg = const_cast<void*>(g);
    __builtin_amdgcn_global_load_lds(
        (__attribute__((address_space(1))) void*)gg,
        (__attribute__((address_space(3))) void*)l, 16, 0, 0);
}

// ---------------------------------------------------------------------------
// Fused Q-projection + KV-projection. 128x128 tiles, BK=64, XOR-swizzled LDS
// (slot cs of row r holds logical 16B chunk cs^(r&7), so fragment ds_read_b128
// spreads 256 dwords evenly over 32 banks). blocks 0..511: qb = hb @ WqT^T;
// blocks 512..799: kvout = kvb @ WkvT^T.
// ---------------------------------------------------------------------------
__global__ __launch_bounds__(256) void proj_all(
    const bf16* __restrict__ hb, const bf16* __restrict__ kvb,
    const bf16* __restrict__ WqT, const bf16* __restrict__ WkvT,
    bf16* __restrict__ qb, bf16* __restrict__ kvout)
{
    __shared__ __align__(16) bf16 As[128 * 64];
    __shared__ __align__(16) bf16 Bs[128 * 64];

    int id = blockIdx.x;
    const bf16 *A, *B; bf16* C; int ldc, m0, n0;
    if (id < 512) {
        A = hb; B = WqT; C = qb; ldc = 2048;
        m0 = (id >> 4) * 128; n0 = (id & 15) * 128;
    } else {
        id -= 512;
        A = kvb; B = WkvT; C = kvout; ldc = 4096;
        m0 = (id >> 5) * 128; n0 = (id & 31) * 128;
    }
    const int tid = threadIdx.x, lane = tid & 63;
    const int wm = ((tid >> 6) >> 1) * 64, wn = ((tid >> 6) & 1) * 64;
    const int fr = lane & 15, fg = lane >> 4;

    f32x4 acc[4][4] = {};

    for (int k0 = 0; k0 < 2048; k0 += 64) {
#pragma unroll
        for (int p = 0; p < 4; ++p) {
            const int c = p * 256 + tid;          // 0..1023
            const int r = c >> 3, cl = (c & 7) ^ (r & 7);
            gld_lds16(A + (long)(m0 + r) * 2048 + k0 + cl * 8, As + c * 8);
            gld_lds16(B + (long)(n0 + r) * 2048 + k0 + cl * 8, Bs + c * 8);
        }
        __syncthreads();
#pragma unroll
        for (int s = 0; s < 2; ++s) {
            const int sl = ((s << 2) + fg) ^ (fr & 7);
            bf16x8 af[4], bg[4];
#pragma unroll
            for (int i = 0; i < 4; ++i)
                af[i] = *(const bf16x8*)(As + (((wm + i * 16 + fr) << 3) + sl) * 8);
#pragma unroll
            for (int j = 0; j < 4; ++j)
                bg[j] = *(const bf16x8*)(Bs + (((wn + j * 16 + fr) << 3) + sl) * 8);
#pragma unroll
            for (int i = 0; i < 4; ++i)
#pragma unroll
                for (int j = 0; j < 4; ++j)
                    acc[i][j] = __builtin_amdgcn_mfma_f32_16x16x32_bf16(
                        af[i], bg[j], acc[i][j], 0, 0, 0);
        }
        __syncthreads();
    }

    const int er = fg * 4;
#pragma unroll
    for (int i = 0; i < 4; ++i)
#pragma unroll
        for (int j = 0; j < 4; ++j) {
            const int n = n0 + wn + j * 16 + fr;
#pragma unroll
            for (int r = 0; r < 4; ++r)
                C[(long)(m0 + wm + i * 16 + er + r) * ldc + n] = (bf16)acc[i][j][r];
        }
}

// ---------------------------------------------------------------------------
// Final GEMM: out(4096x2048 fp32) = aob(4096x2048) @ WoT^T. BK=64 swizzled.
// ---------------------------------------------------------------------------
__global__ __launch_bounds__(256) void gemm_final(
    const bf16* __restrict__ A, const bf16* __restrict__ B, float* __restrict__ C)
{
    __shared__ __align__(16) bf16 As[128 * 64];
    __shared__ __align__(16) bf16 Bs[128 * 64];

    const int m0 = blockIdx.y * 128, n0 = blockIdx.x * 128;
    const int tid = threadIdx.x, lane = tid & 63;
    const int wm = ((tid >> 6) >> 1) * 64, wn = ((tid >> 6) & 1) * 64;
    const int fr = lane & 15, fg = lane >> 4;

    f32x4 acc[4][4] = {};

    for (int k0 = 0; k0 < 2048; k0 += 64) {
#pragma unroll
        for (int p = 0; p < 4; ++p) {
            const int c = p * 256 + tid;
            const int r = c >> 3, cl = (c & 7) ^ (r & 7);
            gld_lds16(A + (long)(m0 + r) * 2048 + k0 + cl * 8, As + c * 8);
            gld_lds16(B + (long)(n0 + r) * 2048 + k0 + cl * 8, Bs + c * 8);
        }
        __syncthreads();
#pragma unroll
        for (int s = 0; s < 2; ++s) {
            const int sl = ((s << 2) + fg) ^ (fr & 7);
            bf16x8 af[4], bg[4];
#pragma unroll
            for (int i = 0; i < 4; ++i)
                af[i] = *(const bf16x8*)(As + (((wm + i * 16 + fr) << 3) + sl) * 8);
#pragma unroll
            for (int j = 0; j < 4; ++j)
                bg[j] = *(const bf16x8*)(Bs + (((wn + j * 16 + fr) << 3) + sl) * 8);
#pragma unroll
            for (int i = 0; i < 4; ++i)
#pragma unroll
                for (int j = 0; j < 4; ++j)
                    acc[i][j] = __builtin_amdgcn_mfma_f32_16x16x32_bf16(
                        af[i], bg[j], acc[i][j], 0, 0, 0);
        }
        __syncthreads();
    }

    const int er = fg * 4;
#pragma unroll
    for (int i = 0; i < 4; ++i)
#pragma unroll
        for (int j = 0; j < 4; ++j) {
            const int n = n0 + wn + j * 16 + fr;
#pragma unroll
            for (int r = 0; r < 4; ++r)
                C[(long)(m0 + wm + i * 16 + er + r) * 2048 + n] = acc[i][j][r];
        }
}

// ---------------------------------------------------------------------------
// Merged RMSNorm (D=2048) + cast for all three input tensors.
// blocks 0..4095: hidden -> hb ; 4096..4223: workspace -> kvb ;
// 4224..5247: correction -> kvb (offset 64 within each batch of 576).
// ---------------------------------------------------------------------------
__global__ __launch_bounds__(256) void rmsnorm_all(
    const float* __restrict__ hidden, const float* __restrict__ wsp,
    const float* __restrict__ corr, const float* __restrict__ lnq,
    const float* __restrict__ lnkv, bf16* __restrict__ hb, bf16* __restrict__ kvb)
{
    const int r = blockIdx.x;
    const float* xr; const float* w; bf16* yr;
    if (r < 4096) {
        xr = hidden + (long)r * D_DIM; w = lnq; yr = hb + (long)r * D_DIM;
    } else if (r < 4224) {
        const int rr = r - 4096;
        xr = wsp + (long)rr * D_DIM; w = lnkv;
        yr = kvb + ((long)(rr >> 6) * NKV + (rr & 63)) * D_DIM;
    } else {
        const int rr = r - 4224;
        xr = corr + (long)rr * D_DIM; w = lnkv;
        yr = kvb + ((long)(rr >> 9) * NKV + 64 + (rr & 511)) * D_DIM;
    }
    const int t = threadIdx.x;

    float4 v0 = *(const float4*)(xr + t * 4);
    float4 v1 = *(const float4*)(xr + 1024 + t * 4);
    float ss = v0.x * v0.x + v0.y * v0.y + v0.z * v0.z + v0.w * v0.w
             + v1.x * v1.x + v1.y * v1.y + v1.z * v1.z + v1.w * v1.w;
#pragma unroll
    for (int off = 32; off; off >>= 1) ss += __shfl_xor(ss, off);
    __shared__ float p[4];
    if ((t & 63) == 0) p[t >> 6] = ss;
    __syncthreads();
    const float rs = rsqrtf((p[0] + p[1] + p[2] + p[3]) * (1.0f / 2048.0f) + 1e-6f);

    float4 w0 = *(const float4*)(w + t * 4);
    float4 w1 = *(const float4*)(w + 1024 + t * 4);
    bf16x4 o0 = { (bf16)(v0.x * rs * w0.x), (bf16)(v0.y * rs * w0.y),
                  (bf16)(v0.z * rs * w0.z), (bf16)(v0.w * rs * w0.w) };
    bf16x4 o1 = { (bf16)(v1.x * rs * w1.x), (bf16)(v1.y * rs * w1.y),
                  (bf16)(v1.z * rs * w1.z), (bf16)(v1.w * rs * w1.w) };
    *(bf16x4*)(yr + t * 4) = o0;
    *(bf16x4*)(yr + 1024 + t * 4) = o1;
}

// ---------------------------------------------------------------------------
// Cast 2048x2048 fp32 weight -> bf16, transposed.
// ---------------------------------------------------------------------------
__global__ __launch_bounds__(256) void wcast_t(
    const float* __restrict__ w0, const float* __restrict__ w1,
    const float* __restrict__ w2, const float* __restrict__ w3,
    bf16* __restrict__ o0, bf16* __restrict__ o1,
    bf16* __restrict__ o2, bf16* __restrict__ o3)
{
    const float* in; bf16* out;
    switch (blockIdx.z) {
        case 0:  in = w0; out = o0; break;
        case 1:  in = w1; out = o1; break;
        case 2:  in = w2; out = o2; break;
        default: in = w3; out = o3; break;
    }
    __shared__ float tile[32][33];
    const int t  = threadIdx.x;
    const int r0 = blockIdx.y * 32, c0 = blockIdx.x * 32;
    const int r = t >> 3, c = (t & 7) * 4;
    float4 v = *(const float4*)(in + (long)(r0 + r) * 2048 + c0 + c);
    tile[r][c] = v.x; tile[r][c + 1] = v.y; tile[r][c + 2] = v.z; tile[r][c + 3] = v.w;
    __syncthreads();
    bf16x4 o = { (bf16)tile[c][r], (bf16)tile[c + 1][r],
                 (bf16)tile[c + 2][r], (bf16)tile[c + 3][r] };
    *(bf16x4*)(out + (long)(c0 + r) * 2048 + r0 + c) = o;
}

// ---------------------------------------------------------------------------
// V part of kvout (B,576,4096) at col 2048+h*128 -> vt (B,H,128,576)
// ---------------------------------------------------------------------------
__global__ __launch_bounds__(256) void vtrans(
    const bf16* __restrict__ kv, bf16* __restrict__ vt)
{
    const int z = blockIdx.z, bb = z >> 4, hh = z & 15;
    __shared__ bf16 tile[32][36];
    const int t  = threadIdx.x;
    const int d0 = blockIdx.x * 32, s0 = blockIdx.y * 32;
    const int r = t >> 3, c = (t & 7) * 4;
    bf16x4 val = *(const bf16x4*)(kv + (long)(bb * NKV + s0 + r) * 4096 + 2048 + hh * 128 + d0 + c);
    tile[r][c] = val[0]; tile[r][c + 1] = val[1];
    tile[r][c + 2] = val[2]; tile[r][c + 3] = val[3];
    __syncthreads();
    bf16x4 o = { tile[c][r], tile[c + 1][r], tile[c + 2][r], tile[c + 3][r] };
    *(bf16x4*)(vt + ((long)z * 128 + d0 + r) * NKV + s0 + c) = o;
}

// ---------------------------------------------------------------------------
// Flash attention: q-tile 64, kv-chunk 64 (9 chunks), online softmax.
// Q fragments in registers; K/VT staged via XOR-swizzled global_load_lds.
// grid (T/64, H, B), 256 threads.
// ---------------------------------------------------------------------------
__global__ __launch_bounds__(256, 4) void flash_attn(
    const bf16* __restrict__ Q, const bf16* __restrict__ KV,
    const bf16* __restrict__ VT, const int* __restrict__ cmask,
    bf16* __restrict__ O)
{
    __shared__ __align__(16) bf16 Ks[64 * 128];   // swizzled; reused as Ps
    __shared__ __align__(16) bf16 VTs[128 * 64];  // swizzled

    const int qt = blockIdx.x, h = blockIdx.y, b = blockIdx.z;
    const int tid = threadIdx.x, lane = tid & 63, w = tid >> 6;
    const int fr = lane & 15, fg = lane >> 4;

    const bf16* qbase = Q + ((long)(b * 2048 + qt * 64)) * 2048 + h * 128;
    bf16x8 qf[4];
#pragma unroll
    for (int s = 0; s < 4; ++s)
        qf[s] = *(const bf16x8*)(qbase + (long)(w * 16 + fr) * 2048 + s * 32 + fg * 8);

    float m_r[4], l_r[4];
    f32x4 acc_o[8];
#pragma unroll
    for (int r = 0; r < 4; ++r) { m_r[r] = -3.0e38f; l_r[r] = 0.f; }
#pragma unroll
    for (int j = 0; j < 8; ++j) acc_o[j] = (f32x4){0.f, 0.f, 0.f, 0.f};

    const float scale2 = 0.12752792330124195f;  // (1/sqrt(128)) * log2(e)
    const bf16* kbase = KV + (long)b * NKV * 4096 + h * 128;
    const bf16* vbase = VT + ((long)(b * 16 + h)) * 128 * NKV;

    for (int kc = 0; kc < 9; ++kc) {
        const int kv0 = kc * 64;
#pragma unroll
        for (int p = 0; p < 4; ++p) {
            const int c = p * 256 + tid;
            const int r = c >> 4, cs = c & 15, cl = cs ^ (r & 15);
            gld_lds16(kbase + (long)(kv0 + r) * 4096 + cl * 8, Ks + c * 8);
        }
#pragma unroll
        for (int p = 0; p < 4; ++p) {
            const int c = p * 256 + tid;
            const int r = c >> 3, cs = c & 7, cl = cs ^ (r & 7);
            gld_lds16(vbase + (long)r * NKV + kv0 + cl * 8, VTs + c * 8);
        }
        __syncthreads();                     // (a) staging visible

        f32x4 acc_s[4] = {};
#pragma unroll
        for (int s = 0; s < 4; ++s) {
#pragma unroll
            for (int j = 0; j < 4; ++j) {
                bf16x8 bg = *(const bf16x8*)(Ks +
                    ((j * 16 + fr) * 16 + ((s * 4 + fg) ^ fr)) * 8);
                acc_s[j] = __builtin_amdgcn_mfma_f32_16x16x32_bf16(qf[s], bg, acc_s[j], 0, 0, 0);
            }
        }

        float bias[4];
#pragma unroll
        for (int j = 0; j < 4; ++j) {
            const int kv = kv0 + j * 16 + fr;
            const bool valid = (kv < 64) || (cmask[b * 512 + kv - 64] != 0);
            bias[j] = valid ? 0.f : -1e30f;
        }
        float s_f[4][4];
        float mc[4] = {-3.0e38f, -3.0e38f, -3.0e38f, -3.0e38f};
#pragma unroll
        for (int j = 0; j < 4; ++j)
#pragma unroll
            for (int r = 0; r < 4; ++r) {
                float v = fmaf(acc_s[j][r], scale2, bias[j]);
                s_f[j][r] = v; mc[r] = fmaxf(mc[r], v);
            }
#pragma unroll
        for (int r = 0; r < 4; ++r) {
            mc[r] = fmaxf(mc[r], __shfl_xor(mc[r], 1));
            mc[r] = fmaxf(mc[r], __shfl_xor(mc[r], 2));
            mc[r] = fmaxf(mc[r], __shfl_xor(mc[r], 4));
            mc[r] = fmaxf(mc[r], __shfl_xor(mc[r], 8));
        }
        float alpha[4];
#pragma unroll
        for (int r = 0; r < 4; ++r) {
            const float mn = fmaxf(m_r[r], mc[r]);
            alpha[r] = __builtin_amdgcn_exp2f(m_r[r] - mn);
            m_r[r] = mn;
        }
        float rs[4] = {0.f, 0.f, 0.f, 0.f};
#pragma unroll
        for (int j = 0; j < 4; ++j)
#pragma unroll
            for (int r = 0; r < 4; ++r) {
                const float pv = __builtin_amdgcn_exp2f(s_f[j][r] - m_r[r]);
                s_f[j][r] = pv; rs[r] += pv;
            }
#pragma unroll
        for (int r = 0; r < 4; ++r) {
            rs[r] += __shfl_xor(rs[r], 1);
            rs[r] += __shfl_xor(rs[r], 2);
            rs[r] += __shfl_xor(rs[r], 4);
            rs[r] += __shfl_xor(rs[r], 8);
            l_r[r] = l_r[r] * alpha[r] + rs[r];
        }
#pragma unroll
        for (int j = 0; j < 8; ++j)
#pragma unroll
            for (int r = 0; r < 4; ++r) acc_o[j][r] *= alpha[r];

        __syncthreads();                     // (b) Ks reads done before overwrite

        bf16* Ps = Ks;
#pragma unroll
        for (int j = 0; j < 4; ++j)
#pragma unroll
            for (int r = 0; r < 4; ++r)
                Ps[(w * 16 + fg * 4 + r) * 72 + j * 16 + fr] = (bf16)s_f[j][r];
        // no barrier: each wave reads only rows it wrote (in-order DS ops)

#pragma unroll
        for (int s2 = 0; s2 < 2; ++s2) {
            bf16x8 af = *(const bf16x8*)(Ps + (w * 16 + fr) * 72 + s2 * 32 + fg * 8);
#pragma unroll
            for (int jd = 0; jd < 8; ++jd) {
                bf16x8 bg = *(const bf16x8*)(VTs +
                    ((jd * 16 + fr) * 8 + ((s2 * 4 + fg) ^ (fr & 7))) * 8);
                acc_o[jd] = __builtin_amdgcn_mfma_f32_16x16x32_bf16(af, bg, acc_o[jd], 0, 0, 0);
            }
        }
        __syncthreads();                     // (c) P/VT reads done before next stage
    }

    bf16* obase = O + ((long)(b * 2048 + qt * 64)) * 2048 + h * 128;
#pragma unroll
    for (int r = 0; r < 4; ++r) {
        const float inv = 1.0f / l_r[r];
        const int row = w * 16 + fg * 4 + r;
#pragma unroll
        for (int jd = 0; jd < 8; ++jd)
            obase[(long)row * 2048 + jd * 16 + fr] = (bf16)(acc_o[jd][r] * inv);
    }
}

// ---------------------------------------------------------------------------
extern "C" void kernel_launch(void* const* d_in, const int* in_sizes, int n_in,
                              void* d_out, int out_size, void* d_ws, size_t ws_size,
                              hipStream_t stream)
{
    const float* hidden = (const float*)d_in[0];
    const float* wsp    = (const float*)d_in[1];
    const float* corr   = (const float*)d_in[2];
    const int*   cmask  = (const int*)d_in[3];
    const float* lnq    = (const float*)d_in[4];
    const float* lnkv   = (const float*)d_in[5];
    const float* Wq     = (const float*)d_in[6];
    const float* Wk     = (const float*)d_in[7];
    const float* Wv     = (const float*)d_in[8];
    const float* Wo     = (const float*)d_in[9];
    float* out = (float*)d_out;

    char* ws = (char*)d_ws;
    size_t off = 0;
    auto alloc = [&](size_t sz) { void* p = ws + off; off += (sz + 255) & ~(size_t)255; return p; };

    bf16* WqT   = (bf16*)alloc(2048ull * 2048 * 2);
    bf16* WkvT  = (bf16*)alloc(4096ull * 2048 * 2);   // [WkT ; WvT]
    bf16* WoT   = (bf16*)alloc(2048ull * 2048 * 2);
    bf16* hb    = (bf16*)alloc(4096ull * 2048 * 2);
    bf16* kvb   = (bf16*)alloc(1152ull * 2048 * 2);
    bf16* qb    = (bf16*)alloc(4096ull * 2048 * 2);
    bf16* kvout = (bf16*)alloc(1152ull * 4096 * 2);   // (B,576,4096): [K|V]
    bf16* vtb   = (bf16*)alloc(4096ull * NKV * 2);    // (B,H,128,576)
    bf16* aob   = (bf16*)alloc(4096ull * 2048 * 2);

    // 1) weights -> bf16 transposed (WkT,WvT stacked into WkvT)
    wcast_t<<<dim3(64, 64, 4), 256, 0, stream>>>(
        Wq, Wk, Wv, Wo, WqT, WkvT, WkvT + 2048ull * 2048, WoT);
    // 2) merged rmsnorm + cast (hidden / workspace / correction)
    rmsnorm_all<<<5248, 256, 0, stream>>>(hidden, wsp, corr, lnq, lnkv, hb, kvb);
    // 3) fused Q + KV projections (one launch, 800 blocks)
    proj_all<<<800, 256, 0, stream>>>(hb, kvb, WqT, WkvT, qb, kvout);
    // 4) V transpose per head
    vtrans<<<dim3(4, 18, 32), 256, 0, stream>>>(kvout, vtb);
    // 5) fused flash attention
    flash_attn<<<dim3(32, 16, 2), 256, 0, stream>>>(qb, kvout, vtb, cmask, aob);
    // 6) final: out = attn_out @ Wo (fp32 out)
    gemm_final<<<dim3(16, 32), 256, 0, stream>>>(aob, WoT, out);
}

// Round 7
// 324.473 us; speedup vs baseline: 1.4271x; 1.0200x over previous
//
#include <hip/hip_runtime.h>
#include <hip/hip_bf16.h>
#include <math.h>

typedef __bf16 bf16;
typedef __attribute__((ext_vector_type(8))) __bf16 bf16x8;
typedef __attribute__((ext_vector_type(4))) __bf16 bf16x4;
typedef __attribute__((ext_vector_type(4))) float f32x4;

#define D_DIM 2048
#define NKV   576

__device__ inline void gld_lds16(const void* g, void* l) {
    void* gg = const_cast<void*>(g);
    __builtin_amdgcn_global_load_lds(
        (__attribute__((address_space(1))) void*)gg,
        (__attribute__((address_space(3))) void*)l, 16, 0, 0);
}

// ---------------------------------------------------------------------------
// prep: blocks 0..16383 = weight cast+transpose (4 weights, 64x64 tiles of 32)
//       blocks 16384..21631 = rmsnorm+cast (hidden / workspace / correction)
// ---------------------------------------------------------------------------
__global__ __launch_bounds__(256) void prep(
    const float* __restrict__ hidden, const float* __restrict__ wsp,
    const float* __restrict__ corr, const float* __restrict__ lnq,
    const float* __restrict__ lnkv,
    const float* __restrict__ Wq, const float* __restrict__ Wk,
    const float* __restrict__ Wv, const float* __restrict__ Wo,
    bf16* __restrict__ hb, bf16* __restrict__ kvb,
    bf16* __restrict__ WqT, bf16* __restrict__ WkvT, bf16* __restrict__ WoT)
{
    __shared__ float tile[32][33];
    __shared__ float p[4];
    const int id = blockIdx.x, t = threadIdx.x;

    if (id < 16384) {
        const int wz = id >> 12, wy = (id >> 6) & 63, wx = id & 63;
        const float* in; bf16* out;
        switch (wz) {
            case 0:  in = Wq; out = WqT; break;
            case 1:  in = Wk; out = WkvT; break;
            case 2:  in = Wv; out = WkvT + 2048ull * 2048; break;
            default: in = Wo; out = WoT; break;
        }
        const int r0 = wy * 32, c0 = wx * 32;
        const int r = t >> 3, c = (t & 7) * 4;
        float4 v = *(const float4*)(in + (long)(r0 + r) * 2048 + c0 + c);
        tile[r][c] = v.x; tile[r][c + 1] = v.y;
        tile[r][c + 2] = v.z; tile[r][c + 3] = v.w;
        __syncthreads();
        bf16x4 o = { (bf16)tile[c][r], (bf16)tile[c + 1][r],
                     (bf16)tile[c + 2][r], (bf16)tile[c + 3][r] };
        *(bf16x4*)(out + (long)(c0 + r) * 2048 + r0 + c) = o;
        return;
    }

    const int rr0 = id - 16384;
    const float* xr; const float* w; bf16* yr;
    if (rr0 < 4096) {
        xr = hidden + (long)rr0 * D_DIM; w = lnq; yr = hb + (long)rr0 * D_DIM;
    } else if (rr0 < 4224) {
        const int rr = rr0 - 4096;
        xr = wsp + (long)rr * D_DIM; w = lnkv;
        yr = kvb + ((long)(rr >> 6) * NKV + (rr & 63)) * D_DIM;
    } else {
        const int rr = rr0 - 4224;
        xr = corr + (long)rr * D_DIM; w = lnkv;
        yr = kvb + ((long)(rr >> 9) * NKV + 64 + (rr & 511)) * D_DIM;
    }

    float4 v0 = *(const float4*)(xr + t * 4);
    float4 v1 = *(const float4*)(xr + 1024 + t * 4);
    float ss = v0.x * v0.x + v0.y * v0.y + v0.z * v0.z + v0.w * v0.w
             + v1.x * v1.x + v1.y * v1.y + v1.z * v1.z + v1.w * v1.w;
#pragma unroll
    for (int off = 32; off; off >>= 1) ss += __shfl_xor(ss, off);
    if ((t & 63) == 0) p[t >> 6] = ss;
    __syncthreads();
    const float rs = rsqrtf((p[0] + p[1] + p[2] + p[3]) * (1.0f / 2048.0f) + 1e-6f);

    float4 w0 = *(const float4*)(w + t * 4);
    float4 w1 = *(const float4*)(w + 1024 + t * 4);
    bf16x4 o0 = { (bf16)(v0.x * rs * w0.x), (bf16)(v0.y * rs * w0.y),
                  (bf16)(v0.z * rs * w0.z), (bf16)(v0.w * rs * w0.w) };
    bf16x4 o1 = { (bf16)(v1.x * rs * w1.x), (bf16)(v1.y * rs * w1.y),
                  (bf16)(v1.z * rs * w1.z), (bf16)(v1.w * rs * w1.w) };
    *(bf16x4*)(yr + t * 4) = o0;
    *(bf16x4*)(yr + 1024 + t * 4) = o1;
}

// ---------------------------------------------------------------------------
// Fused Q + KV projections. 128x128 tiles, BK=64, XOR-swizzled LDS staging.
// blocks 0..511:   qb = hb @ WqT^T            (normal bf16 epilogue)
// blocks 512..799: [K|V] = kvb @ WkvT^T
//     n0 < 2048 -> K block: write kb rows (ldc 2048)
//     n0 >= 2048 -> V block: LDS-transpose epilogue, write vtb (B,H,128,576)
// ---------------------------------------------------------------------------
__global__ __launch_bounds__(256) void proj_all(
    const bf16* __restrict__ hb, const bf16* __restrict__ kvb,
    const bf16* __restrict__ WqT, const bf16* __restrict__ WkvT,
    bf16* __restrict__ qb, bf16* __restrict__ kb, bf16* __restrict__ vtb)
{
    __shared__ __align__(16) bf16 smem[128 * 132];   // staging (32KB) / transpose
    bf16* As = smem;
    bf16* Bs = smem + 128 * 64;

    int id = blockIdx.x;
    const bf16 *A, *B; int m0, n0; bool isQ;
    if (id < 512) {
        isQ = true; A = hb; B = WqT;
        m0 = (id >> 4) * 128; n0 = (id & 15) * 128;
    } else {
        id -= 512;
        isQ = false; A = kvb; B = WkvT;
        m0 = (id >> 5) * 128; n0 = (id & 31) * 128;
    }
    const int tid = threadIdx.x, lane = tid & 63;
    const int wm = ((tid >> 6) >> 1) * 64, wn = ((tid >> 6) & 1) * 64;
    const int fr = lane & 15, fg = lane >> 4;

    f32x4 acc[4][4] = {};

    for (int k0 = 0; k0 < 2048; k0 += 64) {
#pragma unroll
        for (int p = 0; p < 4; ++p) {
            const int c = p * 256 + tid;          // 0..1023
            const int r = c >> 3, cl = (c & 7) ^ (r & 7);
            gld_lds16(A + (long)(m0 + r) * 2048 + k0 + cl * 8, As + c * 8);
            gld_lds16(B + (long)(n0 + r) * 2048 + k0 + cl * 8, Bs + c * 8);
        }
        __syncthreads();
#pragma unroll
        for (int s = 0; s < 2; ++s) {
            const int sl = ((s << 2) + fg) ^ (fr & 7);
            bf16x8 af[4], bg[4];
#pragma unroll
            for (int i = 0; i < 4; ++i)
                af[i] = *(const bf16x8*)(As + (((wm + i * 16 + fr) << 3) + sl) * 8);
#pragma unroll
            for (int j = 0; j < 4; ++j)
                bg[j] = *(const bf16x8*)(Bs + (((wn + j * 16 + fr) << 3) + sl) * 8);
#pragma unroll
            for (int i = 0; i < 4; ++i)
#pragma unroll
                for (int j = 0; j < 4; ++j)
                    acc[i][j] = __builtin_amdgcn_mfma_f32_16x16x32_bf16(
                        af[i], bg[j], acc[i][j], 0, 0, 0);
        }
        __syncthreads();
    }

    const int er = fg * 4;
    if (isQ || n0 < 2048) {
        bf16* C = isQ ? qb : kb;
        const int ldc = 2048;
#pragma unroll
        for (int i = 0; i < 4; ++i)
#pragma unroll
            for (int j = 0; j < 4; ++j) {
                const int n = n0 + wn + j * 16 + fr;
#pragma unroll
                for (int r = 0; r < 4; ++r)
                    C[(long)(m0 + wm + i * 16 + er + r) * ldc + n] = (bf16)acc[i][j][r];
            }
        return;
    }

    // ---- V block: transpose C-tile through LDS, write vtb (B,H,128,576) ----
    const int h = (n0 - 2048) >> 7;
    // store acc transposed: smem[n_local * 132 + m_local]
#pragma unroll
    for (int i = 0; i < 4; ++i)
#pragma unroll
        for (int j = 0; j < 4; ++j) {
            const int nl = wn + j * 16 + fr;
#pragma unroll
            for (int r = 0; r < 4; ++r)
                smem[nl * 132 + (wm + i * 16 + er + r)] = (bf16)acc[i][j][r];
        }
    __syncthreads();
    // coalesced write-back: 128 d-rows x 128 tokens = 16384 elems, 4 per
    // thread-iter, 256 threads -> p < 16. 4-groups never straddle the batch
    // boundary at token 576 (576 % 4 == 0).
#pragma unroll
    for (int p = 0; p < 16; ++p) {
        const int e = p * 1024 + tid * 4;
        const int d = e >> 7, mloc = e & 127;
        bf16x4 val = *(const bf16x4*)(smem + d * 132 + mloc);
        const int mm = m0 + mloc;
        const int bb = mm >= NKV;
        const int s = mm - bb * NKV;
        *(bf16x4*)(vtb + ((long)((bb * 16 + h) * 128 + d)) * NKV + s) = val;
    }
}

// ---------------------------------------------------------------------------
// Final GEMM: out(4096x2048 fp32) = aob(4096x2048) @ WoT^T. BK=64 swizzled.
// ---------------------------------------------------------------------------
__global__ __launch_bounds__(256) void gemm_final(
    const bf16* __restrict__ A, const bf16* __restrict__ B, float* __restrict__ C)
{
    __shared__ __align__(16) bf16 As[128 * 64];
    __shared__ __align__(16) bf16 Bs[128 * 64];

    const int m0 = blockIdx.y * 128, n0 = blockIdx.x * 128;
    const int tid = threadIdx.x, lane = tid & 63;
    const int wm = ((tid >> 6) >> 1) * 64, wn = ((tid >> 6) & 1) * 64;
    const int fr = lane & 15, fg = lane >> 4;

    f32x4 acc[4][4] = {};

    for (int k0 = 0; k0 < 2048; k0 += 64) {
#pragma unroll
        for (int p = 0; p < 4; ++p) {
            const int c = p * 256 + tid;
            const int r = c >> 3, cl = (c & 7) ^ (r & 7);
            gld_lds16(A + (long)(m0 + r) * 2048 + k0 + cl * 8, As + c * 8);
            gld_lds16(B + (long)(n0 + r) * 2048 + k0 + cl * 8, Bs + c * 8);
        }
        __syncthreads();
#pragma unroll
        for (int s = 0; s < 2; ++s) {
            const int sl = ((s << 2) + fg) ^ (fr & 7);
            bf16x8 af[4], bg[4];
#pragma unroll
            for (int i = 0; i < 4; ++i)
                af[i] = *(const bf16x8*)(As + (((wm + i * 16 + fr) << 3) + sl) * 8);
#pragma unroll
            for (int j = 0; j < 4; ++j)
                bg[j] = *(const bf16x8*)(Bs + (((wn + j * 16 + fr) << 3) + sl) * 8);
#pragma unroll
            for (int i = 0; i < 4; ++i)
#pragma unroll
                for (int j = 0; j < 4; ++j)
                    acc[i][j] = __builtin_amdgcn_mfma_f32_16x16x32_bf16(
                        af[i], bg[j], acc[i][j], 0, 0, 0);
        }
        __syncthreads();
    }

    const int er = fg * 4;
#pragma unroll
    for (int i = 0; i < 4; ++i)
#pragma unroll
        for (int j = 0; j < 4; ++j) {
            const int n = n0 + wn + j * 16 + fr;
#pragma unroll
            for (int r = 0; r < 4; ++r)
                C[(long)(m0 + wm + i * 16 + er + r) * 2048 + n] = acc[i][j][r];
        }
}

// ---------------------------------------------------------------------------
// Flash attention: q-tile 64, kv-chunk 64 (9 chunks), online softmax.
// Q fragments in registers; K/VT staged via XOR-swizzled global_load_lds.
// K from kb (B,576,2048); VT from vtb (B,H,128,576). grid (T/64, H, B).
// ---------------------------------------------------------------------------
__global__ __launch_bounds__(256, 4) void flash_attn(
    const bf16* __restrict__ Q, const bf16* __restrict__ K,
    const bf16* __restrict__ VT, const int* __restrict__ cmask,
    bf16* __restrict__ O)
{
    __shared__ __align__(16) bf16 Ks[64 * 128];   // swizzled; reused as Ps
    __shared__ __align__(16) bf16 VTs[128 * 64];  // swizzled

    const int qt = blockIdx.x, h = blockIdx.y, b = blockIdx.z;
    const int tid = threadIdx.x, lane = tid & 63, w = tid >> 6;
    const int fr = lane & 15, fg = lane >> 4;

    const bf16* qbase = Q + ((long)(b * 2048 + qt * 64)) * 2048 + h * 128;
    bf16x8 qf[4];
#pragma unroll
    for (int s = 0; s < 4; ++s)
        qf[s] = *(const bf16x8*)(qbase + (long)(w * 16 + fr) * 2048 + s * 32 + fg * 8);

    float m_r[4], l_r[4];
    f32x4 acc_o[8];
#pragma unroll
    for (int r = 0; r < 4; ++r) { m_r[r] = -3.0e38f; l_r[r] = 0.f; }
#pragma unroll
    for (int j = 0; j < 8; ++j) acc_o[j] = (f32x4){0.f, 0.f, 0.f, 0.f};

    const float scale2 = 0.12752792330124195f;  // (1/sqrt(128)) * log2(e)
    const bf16* kbase = K + (long)b * NKV * 2048 + h * 128;
    const bf16* vbase = VT + ((long)(b * 16 + h)) * 128 * NKV;

    for (int kc = 0; kc < 9; ++kc) {
        const int kv0 = kc * 64;
#pragma unroll
        for (int p = 0; p < 4; ++p) {
            const int c = p * 256 + tid;
            const int r = c >> 4, cs = c & 15, cl = cs ^ (r & 15);
            gld_lds16(kbase + (long)(kv0 + r) * 2048 + cl * 8, Ks + c * 8);
        }
#pragma unroll
        for (int p = 0; p < 4; ++p) {
            const int c = p * 256 + tid;
            const int r = c >> 3, cs = c & 7, cl = cs ^ (r & 7);
            gld_lds16(vbase + (long)r * NKV + kv0 + cl * 8, VTs + c * 8);
        }
        __syncthreads();                     // (a) staging visible

        f32x4 acc_s[4] = {};
#pragma unroll
        for (int s = 0; s < 4; ++s) {
#pragma unroll
            for (int j = 0; j < 4; ++j) {
                bf16x8 bg = *(const bf16x8*)(Ks +
                    ((j * 16 + fr) * 16 + ((s * 4 + fg) ^ fr)) * 8);
                acc_s[j] = __builtin_amdgcn_mfma_f32_16x16x32_bf16(qf[s], bg, acc_s[j], 0, 0, 0);
            }
        }

        float bias[4];
#pragma unroll
        for (int j = 0; j < 4; ++j) {
            const int kv = kv0 + j * 16 + fr;
            const bool valid = (kv < 64) || (cmask[b * 512 + kv - 64] != 0);
            bias[j] = valid ? 0.f : -1e30f;
        }
        float s_f[4][4];
        float mc[4] = {-3.0e38f, -3.0e38f, -3.0e38f, -3.0e38f};
#pragma unroll
        for (int j = 0; j < 4; ++j)
#pragma unroll
            for (int r = 0; r < 4; ++r) {
                float v = fmaf(acc_s[j][r], scale2, bias[j]);
                s_f[j][r] = v; mc[r] = fmaxf(mc[r], v);
            }
#pragma unroll
        for (int r = 0; r < 4; ++r) {
            mc[r] = fmaxf(mc[r], __shfl_xor(mc[r], 1));
            mc[r] = fmaxf(mc[r], __shfl_xor(mc[r], 2));
            mc[r] = fmaxf(mc[r], __shfl_xor(mc[r], 4));
            mc[r] = fmaxf(mc[r], __shfl_xor(mc[r], 8));
        }
        float alpha[4];
#pragma unroll
        for (int r = 0; r < 4; ++r) {
            const float mn = fmaxf(m_r[r], mc[r]);
            alpha[r] = __builtin_amdgcn_exp2f(m_r[r] - mn);
            m_r[r] = mn;
        }
        float rs[4] = {0.f, 0.f, 0.f, 0.f};
#pragma unroll
        for (int j = 0; j < 4; ++j)
#pragma unroll
            for (int r = 0; r < 4; ++r) {
                const float pv = __builtin_amdgcn_exp2f(s_f[j][r] - m_r[r]);
                s_f[j][r] = pv; rs[r] += pv;
            }
#pragma unroll
        for (int r = 0; r < 4; ++r) {
            rs[r] += __shfl_xor(rs[r], 1);
            rs[r] += __shfl_xor(rs[r], 2);
            rs[r] += __shfl_xor(rs[r], 4);
            rs[r] += __shfl_xor(rs[r], 8);
            l_r[r] = l_r[r] * alpha[r] + rs[r];
        }
#pragma unroll
        for (int j = 0; j < 8; ++j)
#pragma unroll
            for (int r = 0; r < 4; ++r) acc_o[j][r] *= alpha[r];

        __syncthreads();                     // (b) Ks reads done before overwrite

        bf16* Ps = Ks;
#pragma unroll
        for (int j = 0; j < 4; ++j)
#pragma unroll
            for (int r = 0; r < 4; ++r)
                Ps[(w * 16 + fg * 4 + r) * 72 + j * 16 + fr] = (bf16)s_f[j][r];
        // no barrier: each wave reads only rows it wrote (in-order DS ops)

#pragma unroll
        for (int s2 = 0; s2 < 2; ++s2) {
            bf16x8 af = *(const bf16x8*)(Ps + (w * 16 + fr) * 72 + s2 * 32 + fg * 8);
#pragma unroll
            for (int jd = 0; jd < 8; ++jd) {
                bf16x8 bg = *(const bf16x8*)(VTs +
                    ((jd * 16 + fr) * 8 + ((s2 * 4 + fg) ^ (fr & 7))) * 8);
                acc_o[jd] = __builtin_amdgcn_mfma_f32_16x16x32_bf16(af, bg, acc_o[jd], 0, 0, 0);
            }
        }
        __syncthreads();                     // (c) P/VT reads done before next stage
    }

    bf16* obase = O + ((long)(b * 2048 + qt * 64)) * 2048 + h * 128;
#pragma unroll
    for (int r = 0; r < 4; ++r) {
        const float inv = 1.0f / l_r[r];
        const int row = w * 16 + fg * 4 + r;
#pragma unroll
        for (int jd = 0; jd < 8; ++jd)
            obase[(long)row * 2048 + jd * 16 + fr] = (bf16)(acc_o[jd][r] * inv);
    }
}

// ---------------------------------------------------------------------------
extern "C" void kernel_launch(void* const* d_in, const int* in_sizes, int n_in,
                              void* d_out, int out_size, void* d_ws, size_t ws_size,
                              hipStream_t stream)
{
    const float* hidden = (const float*)d_in[0];
    const float* wsp    = (const float*)d_in[1];
    const float* corr   = (const float*)d_in[2];
    const int*   cmask  = (const int*)d_in[3];
    const float* lnq    = (const float*)d_in[4];
    const float* lnkv   = (const float*)d_in[5];
    const float* Wq     = (const float*)d_in[6];
    const float* Wk     = (const float*)d_in[7];
    const float* Wv     = (const float*)d_in[8];
    const float* Wo     = (const float*)d_in[9];
    float* out = (float*)d_out;

    char* ws = (char*)d_ws;
    size_t off = 0;
    auto alloc = [&](size_t sz) { void* p = ws + off; off += (sz + 255) & ~(size_t)255; return p; };

    bf16* WqT   = (bf16*)alloc(2048ull * 2048 * 2);
    bf16* WkvT  = (bf16*)alloc(4096ull * 2048 * 2);   // [WkT ; WvT]
    bf16* WoT   = (bf16*)alloc(2048ull * 2048 * 2);
    bf16* hb    = (bf16*)alloc(4096ull * 2048 * 2);
    bf16* kvb   = (bf16*)alloc(1152ull * 2048 * 2);
    bf16* qb    = (bf16*)alloc(4096ull * 2048 * 2);
    bf16* kb    = (bf16*)alloc(1152ull * 2048 * 2);   // K (B,576,2048)
    bf16* vtb   = (bf16*)alloc(4096ull * NKV * 2);    // V^T (B,H,128,576)
    bf16* aob   = (bf16*)alloc(4096ull * 2048 * 2);

    // 1) weights cast+transpose  +  rmsnorm+cast (one launch)
    prep<<<21632, 256, 0, stream>>>(hidden, wsp, corr, lnq, lnkv,
                                    Wq, Wk, Wv, Wo, hb, kvb, WqT, WkvT, WoT);
    // 2) fused Q + KV projections; V written pre-transposed
    proj_all<<<800, 256, 0, stream>>>(hb, kvb, WqT, WkvT, qb, kb, vtb);
    // 3) fused flash attention
    flash_attn<<<dim3(32, 16, 2), 256, 0, stream>>>(qb, kb, vtb, cmask, aob);
    // 4) final: out = attn_out @ Wo (fp32 out)
    gemm_final<<<dim3(16, 32), 256, 0, stream>>>(aob, WoT, out);
}